// Round 1
// baseline (946.716 us; speedup 1.0000x reference)
//
#include <hip/hip_runtime.h>
#include <math.h>

#define BB 8
#define CC 256
#define CQ 32
#define NN 2304   // 48*48

// ---------------------------------------------------------------------------
// Projection kernel: for each branch (x,y) compute
//   q[b][j][0..31]   = wq @ src[:,j] + bq      (stored [B][N][32])
//   k[b][j][0..31]   = wk @ src[:,j] + bk      (stored [B][N][32])
//   vT[b][j][0..255] = wv @ src[:,j] + bv      (stored [B][N][256])
// Classic LDS-tiled fp32 GEMM: 64 pixels x 64 outputs per block, 4x4 micro.
// ---------------------------------------------------------------------------
__global__ __launch_bounds__(256) void proj_kernel(
    const float* __restrict__ x, const float* __restrict__ y,
    const float* __restrict__ wqx, const float* __restrict__ bqx,
    const float* __restrict__ wkx, const float* __restrict__ bkx,
    const float* __restrict__ wvx, const float* __restrict__ bvx,
    const float* __restrict__ wqy, const float* __restrict__ bqy,
    const float* __restrict__ wky, const float* __restrict__ bky,
    const float* __restrict__ wvy, const float* __restrict__ bvy,
    float* __restrict__ ws)
{
    __shared__ float As[16][68];   // [k][pixel], +4 pad
    __shared__ float Wt[16][68];   // [k][out],   +4 pad

    const int t  = threadIdx.x;
    const int pt = blockIdx.x;          // 0..287 : b * 36 + pixel-tile
    const int ot = blockIdx.y;          // 0..4   : output tile of 64
    const int br = blockIdx.z;          // 0..1   : x-branch / y-branch
    const int b  = pt / (NN / 64);
    const int j0 = (pt % (NN / 64)) * 64;

    const float* src = br ? y   : x;
    const float* wq  = br ? wqy : wqx;
    const float* wk  = br ? wky : wkx;
    const float* wv  = br ? wvy : wvx;
    const float* bq  = br ? bqy : bqx;
    const float* bk  = br ? bky : bkx;
    const float* bv  = br ? bvy : bvx;

    const size_t S8 = (size_t)BB * NN * CQ;               // 589824
    float* qbuf = ws + (size_t)br * 2 * S8;               // qx@0, qy@2*S8
    float* kbuf = qbuf + S8;
    float* vbuf = ws + 4 * S8 + (size_t)br * ((size_t)BB * NN * CC);

    // staging roles
    const int kk_a = t >> 4, p4 = t & 15;   // A tile: row kk, float4 col p4
    const int o_w  = t & 63, kg = t >> 6;   // W tile: output o_w, k-group kg
    const float* wrow;
    if (ot == 0) wrow = (o_w < 32) ? (wq + (size_t)o_w * CC)
                                   : (wk + (size_t)(o_w - 32) * CC);
    else         wrow = wv + (size_t)((ot - 1) * 64 + o_w) * CC;

    const int tx = t & 15, ty = t >> 4;     // micro-tile: 4 pixels x 4 outs
    float acc[4][4] = {};

    for (int c0 = 0; c0 < CC; c0 += 16) {
        __syncthreads();
        *(float4*)&As[kk_a][p4 * 4] =
            *(const float4*)&src[((size_t)b * CC + (c0 + kk_a)) * NN + j0 + p4 * 4];
        float4 w4 = *(const float4*)&wrow[c0 + kg * 4];
        Wt[kg * 4 + 0][o_w] = w4.x;
        Wt[kg * 4 + 1][o_w] = w4.y;
        Wt[kg * 4 + 2][o_w] = w4.z;
        Wt[kg * 4 + 3][o_w] = w4.w;
        __syncthreads();
#pragma unroll
        for (int kk = 0; kk < 16; kk++) {
            float4 a4 = *(float4*)&As[kk][tx * 4];
            float4 w4g = *(float4*)&Wt[kk][ty * 4];
            float aa[4] = {a4.x, a4.y, a4.z, a4.w};
            float wwv[4] = {w4g.x, w4g.y, w4g.z, w4g.w};
#pragma unroll
            for (int i = 0; i < 4; i++)
#pragma unroll
                for (int j = 0; j < 4; j++)
                    acc[i][j] += aa[i] * wwv[j];
        }
    }

    // epilogue: bias + store
#pragma unroll
    for (int jj = 0; jj < 4; jj++) {
        int o = ty * 4 + jj;
        if (ot == 0) {
            if (o < 32) {
                float bias = bq[o];
                float* base = qbuf + ((size_t)b * NN + j0) * CQ + o;
#pragma unroll
                for (int ii = 0; ii < 4; ii++)
                    base[(size_t)(tx * 4 + ii) * CQ] = acc[ii][jj] + bias;
            } else {
                float bias = bk[o - 32];
                float* base = kbuf + ((size_t)b * NN + j0) * CQ + (o - 32);
#pragma unroll
                for (int ii = 0; ii < 4; ii++)
                    base[(size_t)(tx * 4 + ii) * CQ] = acc[ii][jj] + bias;
            }
        } else {
            int vo = (ot - 1) * 64 + o;
            float bias = bv[vo];
            float* base = vbuf + ((size_t)b * NN + j0) * CC + vo;
#pragma unroll
            for (int ii = 0; ii < 4; ii++)
                base[(size_t)(tx * 4 + ii) * CC] = acc[ii][jj] + bias;
        }
    }
}

// ---------------------------------------------------------------------------
// Flash attention kernel (fp32, online softmax).
// branch 0: out1 = gamma_x * FlashAttn(Q=qy, K=ky, V=vxT) + x
// branch 1: out2 = gamma_y * FlashAttn(Q=qx, K=kx, V=vyT) + y
// Block: 192 threads, TI=48 query rows, loop over 72 tiles of TJ=32 keys.
// S-phase: thread (r = t>>2, jg = t&3) computes 8 j's of row r.
// PV-phase: thread (rg = t>>5, cg = t&31) owns 8 rows x 8 channels (8x8 acc).
// ---------------------------------------------------------------------------
#define TI 48
#define TJ 32

__global__ __launch_bounds__(192, 3) void flash_kernel(
    const float* __restrict__ x, const float* __restrict__ y,
    const float* __restrict__ gxp, const float* __restrict__ gyp,
    const float* __restrict__ ws, float* __restrict__ out)
{
    __shared__ float Qs[TI][36];    // pad 32->36
    __shared__ float Ks[TJ][36];
    __shared__ float Vs[TJ][CC];
    __shared__ float Ps[TJ][52];    // [j][row], pad 48->52
    __shared__ float Alf[TI];
    __shared__ float Lrow[TI];

    const int t  = threadIdx.x;
    // XCD swizzle: consecutive blockIdx round-robin over 8 XCDs; give each
    // XCD only 2 (batch,branch) combos so V streams stay L2-resident.
    const int id   = blockIdx.x;        // 0..767
    const int xcd  = id & 7;
    const int slot = id >> 3;           // 0..95
    const int combo = xcd * 2 + (slot >= 48);
    const int it   = (slot >= 48) ? (slot - 48) : slot;
    const int b    = combo >> 1;
    const int br   = combo & 1;
    const int i0   = it * TI;

    const size_t S8 = (size_t)BB * NN * CQ;
    const size_t SV = (size_t)BB * NN * CC;
    const float* Qb = ws + (br ? 0 : 2 * S8);      // br0 -> qy, br1 -> qx
    const float* Kb = Qb + S8;
    const float* Vb = ws + 4 * S8 + (br ? SV : 0); // br0 -> vxT, br1 -> vyT
    const float* res = br ? y : x;
    const float gamma = br ? gyp[0] : gxp[0];
    float* op = out + (br ? SV : 0) + (size_t)b * CC * NN;

    // stage Q tile once
    for (int f4 = t; f4 < TI * CQ / 4; f4 += 192) {
        int r = f4 >> 3, c4 = f4 & 7;
        *(float4*)&Qs[r][c4 * 4] =
            *(const float4*)&Qb[((size_t)b * NN + i0 + r) * CQ + c4 * 4];
    }
    __syncthreads();

    const int r_s = t >> 2, jg = t & 3;
    float qreg[CQ];
#pragma unroll
    for (int c = 0; c < CQ; c += 4) {
        float4 q4 = *(float4*)&Qs[r_s][c];
        qreg[c] = q4.x; qreg[c + 1] = q4.y; qreg[c + 2] = q4.z; qreg[c + 3] = q4.w;
    }

    const int rg = t >> 5;   // 0..5
    const int cg = t & 31;   // 0..31
    float acc[8][8] = {};
    float m_run = -1e30f, l_run = 0.0f;

    for (int jt = 0; jt < NN / TJ; jt++) {
        const int jb = jt * TJ;
        __syncthreads();   // previous PV done with Ks/Vs/Ps
        // stage K tile
        for (int f4 = t; f4 < TJ * CQ / 4; f4 += 192) {
            int r = f4 >> 3, c4 = f4 & 7;
            *(float4*)&Ks[r][c4 * 4] =
                *(const float4*)&Kb[((size_t)b * NN + jb + r) * CQ + c4 * 4];
        }
        // stage V tile
        for (int f4 = t; f4 < TJ * CC / 4; f4 += 192) {
            int r = f4 >> 6, c4 = f4 & 63;
            *(float4*)&Vs[r][c4 * 4] =
                *(const float4*)&Vb[((size_t)b * NN + jb + r) * CC + c4 * 4];
        }
        __syncthreads();

        // ---- S phase: 8 dots of length 32 per thread ----
        float s[8];
#pragma unroll
        for (int jj = 0; jj < 8; jj++) {
            int j = jj * 4 + jg;   // interleave jg to avoid LDS conflicts
            float a0 = 0.f, a1 = 0.f, a2 = 0.f, a3 = 0.f;
#pragma unroll
            for (int c = 0; c < CQ; c += 4) {
                float4 k4 = *(float4*)&Ks[j][c];
                a0 += qreg[c]     * k4.x;
                a1 += qreg[c + 1] * k4.y;
                a2 += qreg[c + 2] * k4.z;
                a3 += qreg[c + 3] * k4.w;
            }
            s[jj] = (a0 + a1) + (a2 + a3);
        }
        float tmax = s[0];
#pragma unroll
        for (int jj = 1; jj < 8; jj++) tmax = fmaxf(tmax, s[jj]);
        tmax = fmaxf(tmax, __shfl_xor(tmax, 1));
        tmax = fmaxf(tmax, __shfl_xor(tmax, 2));
        float newm = fmaxf(m_run, tmax);
        float psum = 0.f;
#pragma unroll
        for (int jj = 0; jj < 8; jj++) {
            float p = __expf(s[jj] - newm);
            s[jj] = p;
            psum += p;
        }
        psum += __shfl_xor(psum, 1);
        psum += __shfl_xor(psum, 2);
        float alpha = __expf(m_run - newm);
        l_run = l_run * alpha + psum;
        m_run = newm;
#pragma unroll
        for (int jj = 0; jj < 8; jj++) Ps[jj * 4 + jg][r_s] = s[jj];
        if (jg == 0) Alf[r_s] = alpha;
        __syncthreads();

        // ---- PV phase: 8x8 outer-product micro-kernel ----
#pragma unroll
        for (int ii = 0; ii < 8; ii++) {
            float a = Alf[rg * 8 + ii];
#pragma unroll
            for (int cc = 0; cc < 8; cc++) acc[ii][cc] *= a;
        }
#pragma unroll 4
        for (int j = 0; j < TJ; j++) {
            float4 p0 = *(float4*)&Ps[j][rg * 8];
            float4 p1 = *(float4*)&Ps[j][rg * 8 + 4];
            float4 v0 = *(float4*)&Vs[j][cg * 8];
            float4 v1 = *(float4*)&Vs[j][cg * 8 + 4];
            float pa[8] = {p0.x, p0.y, p0.z, p0.w, p1.x, p1.y, p1.z, p1.w};
            float va[8] = {v0.x, v0.y, v0.z, v0.w, v1.x, v1.y, v1.z, v1.w};
#pragma unroll
            for (int ii = 0; ii < 8; ii++)
#pragma unroll
                for (int cc = 0; cc < 8; cc++)
                    acc[ii][cc] += pa[ii] * va[cc];
        }
    }

    if (jg == 0) Lrow[r_s] = l_run;
    __syncthreads();

    // epilogue: normalize, gamma, residual, store [B][C][N] layout
#pragma unroll
    for (int ii = 0; ii < 8; ii++) {
        int row = i0 + rg * 8 + ii;
        float linv = 1.0f / Lrow[rg * 8 + ii];
#pragma unroll
        for (int cc = 0; cc < 8; cc++) {
            int c = cg * 8 + cc;
            op[(size_t)c * NN + row] = gamma * acc[ii][cc] * linv
                                     + res[((size_t)b * CC + c) * NN + row];
        }
    }
}

extern "C" void kernel_launch(void* const* d_in, const int* in_sizes, int n_in,
                              void* d_out, int out_size, void* d_ws, size_t ws_size,
                              hipStream_t stream)
{
    const float* x   = (const float*)d_in[0];
    const float* y   = (const float*)d_in[1];
    const float* wqx = (const float*)d_in[2];
    const float* bqx = (const float*)d_in[3];
    const float* wkx = (const float*)d_in[4];
    const float* bkx = (const float*)d_in[5];
    const float* wvx = (const float*)d_in[6];
    const float* bvx = (const float*)d_in[7];
    const float* wqy = (const float*)d_in[8];
    const float* bqy = (const float*)d_in[9];
    const float* wky = (const float*)d_in[10];
    const float* bky = (const float*)d_in[11];
    const float* wvy = (const float*)d_in[12];
    const float* bvy = (const float*)d_in[13];
    const float* gx  = (const float*)d_in[14];
    const float* gy  = (const float*)d_in[15];
    float* ws  = (float*)d_ws;
    float* out = (float*)d_out;

    dim3 pg(BB * (NN / 64), 5, 2);   // 288 x 5 x 2
    proj_kernel<<<pg, 256, 0, stream>>>(x, y, wqx, bqx, wkx, bkx, wvx, bvx,
                                        wqy, bqy, wky, bky, wvy, bvy, ws);
    flash_kernel<<<dim3(768), 192, 0, stream>>>(x, y, gx, gy, ws, out);
}

// Round 2
// 359.540 us; speedup vs baseline: 2.6331x; 2.6331x over previous
//
#include <hip/hip_runtime.h>
#include <math.h>

#define BB 8
#define CC 256
#define CQ 32
#define NN 2304   // 48*48

typedef __attribute__((ext_vector_type(8))) short bf16x8;
typedef __attribute__((ext_vector_type(4))) float f32x4;
typedef __attribute__((ext_vector_type(4))) unsigned short u16x4;
typedef unsigned short ushort_t;

static __device__ inline unsigned short f2bf(float f) {
    unsigned u = __builtin_bit_cast(unsigned, f);
    return (unsigned short)((u + 0x7fffu + ((u >> 16) & 1u)) >> 16);
}

// ---------------------------------------------------------------------------
// Projection kernel (fp32 compute, bf16 outputs):
//   q[b][j][0..31], k[b][j][0..31]  (pixel-major, bf16)
//   v[b][c][j]                      (channel-major, bf16)  <- MFMA B-frag ready
// ---------------------------------------------------------------------------
__global__ __launch_bounds__(256) void proj_kernel(
    const float* __restrict__ x, const float* __restrict__ y,
    const float* __restrict__ wqx, const float* __restrict__ bqx,
    const float* __restrict__ wkx, const float* __restrict__ bkx,
    const float* __restrict__ wvx, const float* __restrict__ bvx,
    const float* __restrict__ wqy, const float* __restrict__ bqy,
    const float* __restrict__ wky, const float* __restrict__ bky,
    const float* __restrict__ wvy, const float* __restrict__ bvy,
    ushort_t* __restrict__ ws)
{
    __shared__ float As[16][68];
    __shared__ float Wt[16][68];

    const int t  = threadIdx.x;
    const int pt = blockIdx.x;          // b * 36 + pixel-tile
    const int ot = blockIdx.y;          // 0..4
    const int br = blockIdx.z;          // 0..1
    const int b  = pt / (NN / 64);
    const int j0 = (pt % (NN / 64)) * 64;

    const float* src = br ? y   : x;
    const float* wq  = br ? wqy : wqx;
    const float* wk  = br ? wky : wkx;
    const float* wv  = br ? wvy : wvx;
    const float* bq  = br ? bqy : bqx;
    const float* bk  = br ? bky : bkx;
    const float* bv  = br ? bvy : bvx;

    const size_t S8 = (size_t)BB * NN * CQ;
    const size_t SV = (size_t)BB * NN * CC;
    ushort_t* qbuf = ws + (size_t)br * 2 * S8;
    ushort_t* kbuf = qbuf + S8;
    ushort_t* vbuf = ws + 4 * S8 + (size_t)br * SV;

    const int kk_a = t >> 4, p4 = t & 15;
    const int o_w  = t & 63, kg = t >> 6;
    const float* wrow;
    if (ot == 0) wrow = (o_w < 32) ? (wq + (size_t)o_w * CC)
                                   : (wk + (size_t)(o_w - 32) * CC);
    else         wrow = wv + (size_t)((ot - 1) * 64 + o_w) * CC;

    const int tx = t & 15, ty = t >> 4;
    float acc[4][4] = {};

    for (int c0 = 0; c0 < CC; c0 += 16) {
        __syncthreads();
        *(float4*)&As[kk_a][p4 * 4] =
            *(const float4*)&src[((size_t)b * CC + (c0 + kk_a)) * NN + j0 + p4 * 4];
        float4 w4 = *(const float4*)&wrow[c0 + kg * 4];
        Wt[kg * 4 + 0][o_w] = w4.x;
        Wt[kg * 4 + 1][o_w] = w4.y;
        Wt[kg * 4 + 2][o_w] = w4.z;
        Wt[kg * 4 + 3][o_w] = w4.w;
        __syncthreads();
#pragma unroll
        for (int kk = 0; kk < 16; kk++) {
            float4 a4  = *(float4*)&As[kk][tx * 4];
            float4 w4g = *(float4*)&Wt[kk][ty * 4];
            float aa[4]  = {a4.x, a4.y, a4.z, a4.w};
            float wwv[4] = {w4g.x, w4g.y, w4g.z, w4g.w};
#pragma unroll
            for (int i = 0; i < 4; i++)
#pragma unroll
                for (int j = 0; j < 4; j++)
                    acc[i][j] += aa[i] * wwv[j];
        }
    }

    if (ot == 0) {
        // q/k: pixel-major [b][pixel][32], 4 contiguous outs per store
        bool isq = (ty < 8);
        int ob = (isq ? ty : (ty - 8)) * 4;
        const float* bb = isq ? bq : bk;
        float b4[4] = {bb[ob], bb[ob + 1], bb[ob + 2], bb[ob + 3]};
        ushort_t* dst = (isq ? qbuf : kbuf) + ((size_t)b * NN + j0) * CQ + ob;
#pragma unroll
        for (int ii = 0; ii < 4; ii++) {
            int pix = tx * 4 + ii;
            u16x4 pk;
#pragma unroll
            for (int jj = 0; jj < 4; jj++) pk[jj] = f2bf(acc[ii][jj] + b4[jj]);
            *(u16x4*)(dst + (size_t)pix * CQ) = pk;
        }
    } else {
        // v: channel-major [b][c][pixel], 4 contiguous pixels per store
#pragma unroll
        for (int jj = 0; jj < 4; jj++) {
            int vo = (ot - 1) * 64 + ty * 4 + jj;
            float bias = bv[vo];
            u16x4 pk;
#pragma unroll
            for (int ii = 0; ii < 4; ii++) pk[ii] = f2bf(acc[ii][jj] + bias);
            *(u16x4*)(vbuf + ((size_t)b * CC + vo) * NN + j0 + tx * 4) = pk;
        }
    }
}

// ---------------------------------------------------------------------------
// MFMA flash attention, bf16 inputs / fp32 accumulate.
// Block: 256 thr (4 waves), TI=64 query rows, TJ=64 keys per iteration.
// Wave w: S+softmax for rows 16w..16w+16 (Q/K frags direct from global),
//         PV for all 64 rows x channels [64w, 64w+64) (P,V from LDS).
// ---------------------------------------------------------------------------
#define TI 64
#define TJ 64
#define TJP 72   // pad: row stride 144B -> 2-way bank aliasing (free)

__global__ __launch_bounds__(256, 3) void flash_kernel(
    const float* __restrict__ x, const float* __restrict__ y,
    const float* __restrict__ gxp, const float* __restrict__ gyp,
    const ushort_t* __restrict__ ws, float* __restrict__ out)
{
    __shared__ __align__(16) unsigned char smem[(256 * TJP + TI * TJP) * 2]; // 46080B
    ushort_t* Vs = (ushort_t*)smem;                       // [256][TJP]
    ushort_t* Ps = (ushort_t*)(smem + 256 * TJP * 2);     // [TI][TJP]
    float*    Ob = (float*)smem;                          // [256][20] (epilogue)
    __shared__ __align__(16) float Alf[TI];
    __shared__ __align__(16) float Lrow[TI];

    const int t    = threadIdx.x;
    const int w    = t >> 6;
    const int lane = t & 63;
    const int l15  = lane & 15;
    const int quad = lane >> 4;

    // id -> (xcd=batch, branch, i-tile): each XCD owns one batch (both branches)
    const int id   = blockIdx.x;         // 0..575
    const int b    = id & 7;
    const int slot = id >> 3;            // 0..71
    const int br   = slot >= 36;
    const int it   = br ? slot - 36 : slot;
    const int i0   = it * TI;

    const size_t S8 = (size_t)BB * NN * CQ;
    const size_t SV = (size_t)BB * NN * CC;
    const ushort_t* Qb = ws + (br ? 0 : 2 * S8);   // br0: qy/ky, br1: qx/kx
    const ushort_t* Kb = Qb + S8;
    const ushort_t* Vb = ws + 4 * S8 + (br ? SV : 0);
    const float* res = br ? y : x;
    const float gamma = br ? gyp[0] : gxp[0];
    float* op = out + (size_t)br * SV + (size_t)b * CC * NN;

    // Q fragment (held all kernel): rows i0 + 16w + l15, k = quad*8..+8
    bf16x8 qf = *(const bf16x8*)(Qb + ((size_t)b * NN + i0 + w * 16 + l15) * CQ + quad * 8);

    f32x4 acc[4][4];
#pragma unroll
    for (int i = 0; i < 4; i++)
#pragma unroll
        for (int j = 0; j < 4; j++) acc[i][j] = (f32x4){0.f, 0.f, 0.f, 0.f};
    float m_run[4] = {-1e30f, -1e30f, -1e30f, -1e30f};
    float l_run[4] = {0.f, 0.f, 0.f, 0.f};

    for (int jt = 0; jt < NN / TJ; jt++) {
        const int jb = jt * TJ;
        __syncthreads();   // Vs/Ps free (previous PV done)

        // ---- stage V tile [256][64] -> LDS channel-major ----
        {
            const int ch = t & 7;
#pragma unroll
            for (int rep = 0; rep < 8; rep++) {
                int c = rep * 32 + (t >> 3);
                *(uint4*)&Vs[c * TJP + ch * 8] =
                    *(const uint4*)(Vb + ((size_t)b * CC + c) * NN + jb + ch * 8);
            }
        }

        // ---- S = Q K^T for this wave's 16 rows ----
        bf16x8 kf[4];
        const ushort_t* kp = Kb + ((size_t)b * NN + jb) * CQ + quad * 8;
#pragma unroll
        for (int n = 0; n < 4; n++)
            kf[n] = *(const bf16x8*)(kp + (size_t)(n * 16 + l15) * CQ);
        f32x4 s[4];
#pragma unroll
        for (int n = 0; n < 4; n++)
            s[n] = __builtin_amdgcn_mfma_f32_16x16x32_bf16(qf, kf[n],
                       (f32x4){0.f, 0.f, 0.f, 0.f}, 0, 0, 0);

        // ---- online softmax (row = quad*4+r, cols spread over l15 & n) ----
        float alpha[4];
#pragma unroll
        for (int r = 0; r < 4; r++) {
            float mx = fmaxf(fmaxf(s[0][r], s[1][r]), fmaxf(s[2][r], s[3][r]));
            mx = fmaxf(mx, __shfl_xor(mx, 1));
            mx = fmaxf(mx, __shfl_xor(mx, 2));
            mx = fmaxf(mx, __shfl_xor(mx, 4));
            mx = fmaxf(mx, __shfl_xor(mx, 8));
            float nm = fmaxf(m_run[r], mx);
            alpha[r] = __expf(m_run[r] - nm);
            float sum = 0.f;
#pragma unroll
            for (int n = 0; n < 4; n++) {
                float p = __expf(s[n][r] - nm);
                s[n][r] = p;
                sum += p;
            }
            sum += __shfl_xor(sum, 1);
            sum += __shfl_xor(sum, 2);
            sum += __shfl_xor(sum, 4);
            sum += __shfl_xor(sum, 8);
            l_run[r] = l_run[r] * alpha[r] + sum;
            m_run[r] = nm;
        }
        // P -> LDS (bf16), C-layout scatter
#pragma unroll
        for (int n = 0; n < 4; n++)
#pragma unroll
            for (int r = 0; r < 4; r++)
                Ps[(w * 16 + quad * 4 + r) * TJP + n * 16 + l15] = f2bf(s[n][r]);
        if (l15 == 0) {
            f32x4 av = {alpha[0], alpha[1], alpha[2], alpha[3]};
            *(f32x4*)&Alf[w * 16 + quad * 4] = av;
        }
        __syncthreads();

        // ---- PV: rescale + 32 MFMAs ----
#pragma unroll
        for (int rt = 0; rt < 4; rt++) {
            f32x4 av = *(f32x4*)&Alf[rt * 16 + quad * 4];
#pragma unroll
            for (int ct = 0; ct < 4; ct++)
#pragma unroll
                for (int r = 0; r < 4; r++) acc[rt][ct][r] *= av[r];
        }
#pragma unroll
        for (int ks = 0; ks < 2; ks++) {
            bf16x8 pf[4], vf[4];
#pragma unroll
            for (int rt = 0; rt < 4; rt++)
                pf[rt] = *(const bf16x8*)&Ps[(rt * 16 + l15) * TJP + ks * 32 + quad * 8];
#pragma unroll
            for (int ct = 0; ct < 4; ct++)
                vf[ct] = *(const bf16x8*)&Vs[(w * 64 + ct * 16 + l15) * TJP + ks * 32 + quad * 8];
#pragma unroll
            for (int rt = 0; rt < 4; rt++)
#pragma unroll
                for (int ct = 0; ct < 4; ct++)
                    acc[rt][ct] = __builtin_amdgcn_mfma_f32_16x16x32_bf16(
                        pf[rt], vf[ct], acc[rt][ct], 0, 0, 0);
        }
    }

    if (l15 == 0) {
        f32x4 lv = {l_run[0], l_run[1], l_run[2], l_run[3]};
        *(f32x4*)&Lrow[w * 16 + quad * 4] = lv;
    }
    __syncthreads();

    // ---- epilogue: per 16-row chunk, transpose via LDS, coalesced store ----
    for (int rt = 0; rt < 4; rt++) {
        f32x4 lv = *(f32x4*)&Lrow[rt * 16 + quad * 4];
        f32x4 gi;
#pragma unroll
        for (int r = 0; r < 4; r++) gi[r] = gamma / lv[r];
#pragma unroll
        for (int ct = 0; ct < 4; ct++) {
            int c = w * 64 + ct * 16 + l15;
            f32x4 ov;
#pragma unroll
            for (int r = 0; r < 4; r++) ov[r] = acc[rt][ct][r] * gi[r];
            *(f32x4*)&Ob[c * 20 + quad * 4] = ov;
        }
        __syncthreads();
#pragma unroll
        for (int rep = 0; rep < 4; rep++) {
            int c  = rep * 64 + (t >> 2);
            int p4 = t & 3;
            f32x4 v = *(f32x4*)&Ob[c * 20 + p4 * 4];
            size_t go = ((size_t)b * CC + c) * NN + i0 + rt * 16 + p4 * 4;
            f32x4 r4 = *(const f32x4*)&res[go];
            v += r4;
            *(f32x4*)&op[(size_t)c * NN + i0 + rt * 16 + p4 * 4] = v;
        }
        __syncthreads();
    }
}

extern "C" void kernel_launch(void* const* d_in, const int* in_sizes, int n_in,
                              void* d_out, int out_size, void* d_ws, size_t ws_size,
                              hipStream_t stream)
{
    const float* x   = (const float*)d_in[0];
    const float* y   = (const float*)d_in[1];
    const float* wqx = (const float*)d_in[2];
    const float* bqx = (const float*)d_in[3];
    const float* wkx = (const float*)d_in[4];
    const float* bkx = (const float*)d_in[5];
    const float* wvx = (const float*)d_in[6];
    const float* bvx = (const float*)d_in[7];
    const float* wqy = (const float*)d_in[8];
    const float* bqy = (const float*)d_in[9];
    const float* wky = (const float*)d_in[10];
    const float* bky = (const float*)d_in[11];
    const float* wvy = (const float*)d_in[12];
    const float* bvy = (const float*)d_in[13];
    const float* gx  = (const float*)d_in[14];
    const float* gy  = (const float*)d_in[15];
    ushort_t* ws = (ushort_t*)d_ws;
    float* out = (float*)d_out;

    dim3 pg(BB * (NN / 64), 5, 2);
    proj_kernel<<<pg, 256, 0, stream>>>(x, y, wqx, bqx, wkx, bkx, wvx, bvx,
                                        wqy, bqy, wky, bky, wvy, bvy, ws);
    flash_kernel<<<dim3(576), 256, 0, stream>>>(x, y, gx, gy, ws, out);
}

// Round 3
// 295.855 us; speedup vs baseline: 3.1999x; 1.2153x over previous
//
#include <hip/hip_runtime.h>
#include <math.h>

#define BB 8
#define CC 256
#define CQ 32
#define NN 2304   // 48*48
#define NT 36     // NN/64
#define NJ 36

typedef __attribute__((ext_vector_type(8))) short bf16x8;
typedef __attribute__((ext_vector_type(4))) float f32x4;
typedef __attribute__((ext_vector_type(4))) unsigned short u16x4;
typedef unsigned short ushort_t;
typedef unsigned int u32;

#define LOG2E 1.44269504088896f

static __device__ inline unsigned short f2bf(float f) {
    unsigned u = __builtin_bit_cast(unsigned, f);
    return (unsigned short)((u + 0x7fffu + ((u >> 16) & 1u)) >> 16);
}

static __device__ inline void gld_lds16(const ushort_t* g, ushort_t* l) {
    __builtin_amdgcn_global_load_lds(
        (const __attribute__((address_space(1))) u32*)g,
        (__attribute__((address_space(3))) u32*)l, 16, 0, 0);
}

// workspace layout (ushort units):
//  qx @ 0, kx @ S8, qy @ 2*S8, ky @ 3*S8          (each B*N*32, pixel-major bf16)
//  vx @ 4*S8, vy @ 4*S8+SV                        (each B*C*N, channel-major bf16,
//                                                  16B chunks XOR-swizzled by c&7 per 64px tile)
//  Wall @ 4*S8+2*SV : [2][320][256] bf16          (rows 0-31 Wq*log2e, 32-63 Wk, 64-319 Wv)
//  ball  @ +163840  : [2][320] float biases       (q rows scaled by log2e)
#define S8  ((size_t)BB * NN * CQ)
#define SV  ((size_t)BB * NN * CC)
#define WOFF (4 * S8 + 2 * SV)

// ---------------------------------------------------------------------------
// Weight convert: fp32 -> bf16, fold log2(e) into Wq/bq.
// ---------------------------------------------------------------------------
__global__ __launch_bounds__(256) void wcvt_kernel(
    const float* __restrict__ wqx, const float* __restrict__ bqx,
    const float* __restrict__ wkx, const float* __restrict__ bkx,
    const float* __restrict__ wvx, const float* __restrict__ bvx,
    const float* __restrict__ wqy, const float* __restrict__ bqy,
    const float* __restrict__ wky, const float* __restrict__ bky,
    const float* __restrict__ wvy, const float* __restrict__ bvy,
    ushort_t* __restrict__ ws)
{
    ushort_t* Wall = ws + WOFF;
    float*    ball = (float*)(ws + WOFF + 2 * 320 * 256);

    int id = blockIdx.x * 256 + threadIdx.x;   // 0..40959
    int row = id >> 6;                          // 0..639
    int c4  = (id & 63) * 4;
    int br  = row >= 320;
    int r   = row - br * 320;

    const float* src;
    float scale = 1.0f;
    if (r < 32)      { src = (br ? wqy : wqx) + (size_t)r * CC;        scale = LOG2E; }
    else if (r < 64) { src = (br ? wky : wkx) + (size_t)(r - 32) * CC; }
    else             { src = (br ? wvy : wvx) + (size_t)(r - 64) * CC; }

    float4 v = *(const float4*)(src + c4);
    u16x4 pk;
    pk[0] = f2bf(v.x * scale); pk[1] = f2bf(v.y * scale);
    pk[2] = f2bf(v.z * scale); pk[3] = f2bf(v.w * scale);
    *(u16x4*)(Wall + (size_t)row * CC + c4) = pk;

    if (id < 640) {
        int row2 = id, br2 = row2 >= 320, r2 = row2 - br2 * 320;
        const float* bsrc; float sc2 = 1.0f;
        if (r2 < 32)      { bsrc = (br2 ? bqy : bqx) + r2;        sc2 = LOG2E; }
        else if (r2 < 64) { bsrc = (br2 ? bky : bkx) + (r2 - 32); }
        else              { bsrc = (br2 ? bvy : bvx) + (r2 - 64); }
        ball[row2] = bsrc[0] * sc2;
    }
}

// ---------------------------------------------------------------------------
// Projection via MFMA: block = (b, br, 64-px tile), 4 waves x 16 px, all 320
// outputs. A-frags gathered from fp32 x/y (cvt bf16); B-frags = Wall (global).
// ---------------------------------------------------------------------------
__global__ __launch_bounds__(256, 2) void proj_kernel(
    const float* __restrict__ x, const float* __restrict__ y,
    ushort_t* __restrict__ ws)
{
    __shared__ __align__(16) ushort_t vls[256 * 64];   // 32 KB

    const int t = threadIdx.x, w = t >> 6, lane = t & 63;
    const int l15 = lane & 15, quad = lane >> 4;

    const int id   = blockIdx.x;        // 0..575
    const int b    = id & 7;
    const int rest = id >> 3;           // 0..71
    const int br   = rest >= NT;
    const int tile = br ? rest - NT : rest;

    const float* src = br ? y : x;
    const ushort_t* Wall = ws + WOFF + (size_t)br * 320 * CC;
    const float*    ball = (float*)(ws + WOFF + 2 * 320 * 256) + br * 320;

    ushort_t* qbuf = ws + (size_t)br * 2 * S8;
    ushort_t* kbuf = qbuf + S8;
    ushort_t* vbufg = ws + 4 * S8 + (size_t)br * SV;

    const int px0 = tile * 64 + w * 16;

    // ---- A fragments: X^T[px][c] in bf16, 8 k-chunks ----
    const float* ap = src + (size_t)b * CC * NN + px0 + l15;
    bf16x8 af[8];
#pragma unroll
    for (int q = 0; q < 8; q++) {
        float av[8];
#pragma unroll
        for (int j = 0; j < 8; j++)
            av[j] = ap[(size_t)(q * 32 + quad * 8 + j) * NN];
        union { bf16x8 v; unsigned short u[8]; } tmp;
#pragma unroll
        for (int j = 0; j < 8; j++) tmp.u[j] = f2bf(av[j]);
        af[q] = tmp.v;
    }

    // ---- 20 output tiles x 8 K-chunk MFMAs ----
    const ushort_t* wb = Wall + (size_t)l15 * CC + quad * 8;
    f32x4 acc[20];
#pragma unroll
    for (int ot = 0; ot < 20; ot++) {
        f32x4 a = (f32x4){0.f, 0.f, 0.f, 0.f};
#pragma unroll
        for (int q = 0; q < 8; q++)
            a = __builtin_amdgcn_mfma_f32_16x16x32_bf16(
                    af[q], *(const bf16x8*)(wb + (size_t)(ot * 16) * CC + q * 32),
                    a, 0, 0, 0);
        acc[ot] = a;
    }

    // ---- epilogue: q/k direct, v via LDS transpose+swizzle ----
#pragma unroll
    for (int ot = 0; ot < 4; ot++) {
        int o = ot * 16 + l15;          // 0..63
        float bias = ball[o];
        ushort_t* dst = (o < 32 ? qbuf : kbuf);
        int oc = o & 31;
#pragma unroll
        for (int r = 0; r < 4; r++) {
            int pxl = w * 16 + quad * 4 + r;
            dst[((size_t)b * NN + tile * 64 + pxl) * CQ + oc] = f2bf(acc[ot][r] + bias);
        }
    }
#pragma unroll
    for (int ot = 4; ot < 20; ot++) {
        int o_loc = (ot - 4) * 16 + l15;   // 0..255
        float bias = ball[64 + o_loc];
#pragma unroll
        for (int r = 0; r < 4; r++) {
            int pxl = w * 16 + quad * 4 + r;
            vls[o_loc * 64 + (((pxl >> 3) ^ (o_loc & 7)) * 8) + (pxl & 7)] =
                f2bf(acc[ot][r] + bias);
        }
    }
    __syncthreads();
#pragma unroll
    for (int rep = 0; rep < 8; rep++) {
        int cid = rep * 256 + t;           // 0..2047
        int o_loc = cid >> 3, pc = cid & 7;
        *(uint4*)(vbufg + ((size_t)b * CC + o_loc) * NN + tile * 64 + pc * 8) =
            *(uint4*)&vls[cid * 8];
    }
}

// ---------------------------------------------------------------------------
// Flash attention, no-max softmax (p = 2^s), async double-buffered V.
// ---------------------------------------------------------------------------
#define TI 64
#define TJ 64
#define TJP 72

__global__ __launch_bounds__(256, 2) void flash_kernel(
    const float* __restrict__ x, const float* __restrict__ y,
    const float* __restrict__ gxp, const float* __restrict__ gyp,
    const ushort_t* __restrict__ ws, float* __restrict__ out)
{
    __shared__ __align__(16) ushort_t Vs[2][256 * 64];   // 64 KB, swizzled chunks
    __shared__ __align__(16) ushort_t Ps[TI * TJP];      // 9216 B
    __shared__ __align__(16) float Lrow[TI];
    float* Ob = (float*)&Vs[0][0];                       // epilogue reuse

    const int t = threadIdx.x, w = t >> 6, lane = t & 63;
    const int l15 = lane & 15, quad = lane >> 4;

    const int id   = blockIdx.x;        // 0..575
    const int b    = id & 7;
    const int rest = id >> 3;
    const int br   = rest >= NT;
    const int it   = br ? rest - NT : rest;
    const int i0   = it * TI;

    const ushort_t* Qb = ws + (br ? 0 : 2 * S8);   // br0: qy/ky, br1: qx/kx
    const ushort_t* Kb = Qb + S8;
    const ushort_t* Vb = ws + 4 * S8 + (br ? SV : 0);
    const float* res = br ? y : x;
    const float gamma = br ? gyp[0] : gxp[0];
    float* op = out + (size_t)br * SV + (size_t)b * CC * NN;

    bf16x8 qf = *(const bf16x8*)(Qb + ((size_t)b * NN + i0 + w * 16 + l15) * CQ + quad * 8);

    f32x4 acc[4][4];
#pragma unroll
    for (int i = 0; i < 4; i++)
#pragma unroll
        for (int j = 0; j < 4; j++) acc[i][j] = (f32x4){0.f, 0.f, 0.f, 0.f};
    float l_loc[4] = {0.f, 0.f, 0.f, 0.f};

    // staging geometry: wave w stages channels [w*64, w*64+64)
    const ushort_t* Vg = Vb + (size_t)b * CC * NN
                       + (size_t)(w * 64 + (lane >> 3)) * NN + (lane & 7) * 8;
    const ushort_t* kp = Kb + ((size_t)b * NN + l15) * CQ + quad * 8;

    // prologue: V(0) + kf(0)
    {
        ushort_t* l = &Vs[0][(w * 64) * 64];
#pragma unroll
        for (int is = 0; is < 8; is++)
            gld_lds16(Vg + (size_t)is * 8 * NN, l + is * 512);
    }
    bf16x8 kf[4];
#pragma unroll
    for (int n = 0; n < 4; n++)
        kf[n] = *(const bf16x8*)(kp + (size_t)(n * 16) * CQ);

    for (int jt = 0; jt < NJ; jt++) {
        const int cur = jt & 1;

        // S = Q K^T (registers only)
        f32x4 s[4];
#pragma unroll
        for (int n = 0; n < 4; n++)
            s[n] = __builtin_amdgcn_mfma_f32_16x16x32_bf16(qf, kf[n],
                       (f32x4){0.f, 0.f, 0.f, 0.f}, 0, 0, 0);

        // p = 2^s, per-lane row-sum accumulate, bf16 pack
        unsigned short pu[4][4];
#pragma unroll
        for (int n = 0; n < 4; n++)
#pragma unroll
            for (int r = 0; r < 4; r++) {
                float p = __builtin_amdgcn_exp2f(s[n][r]);
                l_loc[r] += p;
                pu[n][r] = f2bf(p);
            }

        __syncthreads();   // B1: PV(jt-1) done with Ps & other V buf; V(jt) drained
#pragma unroll
        for (int n = 0; n < 4; n++)
#pragma unroll
            for (int r = 0; r < 4; r++)
                Ps[(w * 16 + quad * 4 + r) * TJP + n * 16 + l15] = pu[n][r];
        __syncthreads();   // B2: P visible

        // prefetch V(jt+1) + kf(jt+1): overlap with PV below
        if (jt + 1 < NJ) {
            ushort_t* l = &Vs[cur ^ 1][(w * 64) * 64];
            const ushort_t* g = Vg + (size_t)(jt + 1) * TJ;
#pragma unroll
            for (int is = 0; is < 8; is++)
                gld_lds16(g + (size_t)is * 8 * NN, l + is * 512);
            const ushort_t* kn = kp + (size_t)((jt + 1) * TJ) * CQ;
#pragma unroll
            for (int n = 0; n < 4; n++)
                kf[n] = *(const bf16x8*)(kn + (size_t)(n * 16) * CQ);
        }

        // PV: 32 MFMAs from Ps + Vs[cur]
#pragma unroll
        for (int ks = 0; ks < 2; ks++) {
            bf16x8 pf[4], vf[4];
#pragma unroll
            for (int rt = 0; rt < 4; rt++)
                pf[rt] = *(const bf16x8*)&Ps[(rt * 16 + l15) * TJP + ks * 32 + quad * 8];
#pragma unroll
            for (int ct = 0; ct < 4; ct++) {
                int row = w * 64 + ct * 16 + l15;
                int pc  = (ks * 4 + quad) ^ (l15 & 7);
                vf[ct] = *(const bf16x8*)&Vs[cur][row * 64 + pc * 8];
            }
#pragma unroll
            for (int rt = 0; rt < 4; rt++)
#pragma unroll
                for (int ct = 0; ct < 4; ct++)
                    acc[rt][ct] = __builtin_amdgcn_mfma_f32_16x16x32_bf16(
                        pf[rt], vf[ct], acc[rt][ct], 0, 0, 0);
        }
    }

    // final row-sum reduction across l15
#pragma unroll
    for (int r = 0; r < 4; r++) {
        float l = l_loc[r];
        l += __shfl_xor(l, 1);
        l += __shfl_xor(l, 2);
        l += __shfl_xor(l, 4);
        l += __shfl_xor(l, 8);
        l_loc[r] = l;
    }
    if (l15 == 0) {
        f32x4 lv = {l_loc[0], l_loc[1], l_loc[2], l_loc[3]};
        *(f32x4*)&Lrow[w * 16 + quad * 4] = lv;
    }
    __syncthreads();

    // epilogue: normalize, gamma, residual, coalesced [C][N] store
    for (int rt = 0; rt < 4; rt++) {
        f32x4 lv = *(f32x4*)&Lrow[rt * 16 + quad * 4];
        f32x4 gi;
#pragma unroll
        for (int r = 0; r < 4; r++) gi[r] = gamma / lv[r];
#pragma unroll
        for (int ct = 0; ct < 4; ct++) {
            int c = w * 64 + ct * 16 + l15;
            f32x4 ov;
#pragma unroll
            for (int r = 0; r < 4; r++) ov[r] = acc[rt][ct][r] * gi[r];
            *(f32x4*)&Ob[c * 20 + quad * 4] = ov;
        }
        __syncthreads();
#pragma unroll
        for (int rep = 0; rep < 4; rep++) {
            int c  = rep * 64 + (t >> 2);
            int p4 = t & 3;
            f32x4 v = *(f32x4*)&Ob[c * 20 + p4 * 4];
            size_t go = ((size_t)b * CC + c) * NN + i0 + rt * 16 + p4 * 4;
            f32x4 r4 = *(const f32x4*)&res[go];
            v += r4;
            *(f32x4*)&op[(size_t)c * NN + i0 + rt * 16 + p4 * 4] = v;
        }
        __syncthreads();
    }
}

extern "C" void kernel_launch(void* const* d_in, const int* in_sizes, int n_in,
                              void* d_out, int out_size, void* d_ws, size_t ws_size,
                              hipStream_t stream)
{
    const float* x   = (const float*)d_in[0];
    const float* y   = (const float*)d_in[1];
    const float* wqx = (const float*)d_in[2];
    const float* bqx = (const float*)d_in[3];
    const float* wkx = (const float*)d_in[4];
    const float* bkx = (const float*)d_in[5];
    const float* wvx = (const float*)d_in[6];
    const float* bvx = (const float*)d_in[7];
    const float* wqy = (const float*)d_in[8];
    const float* bqy = (const float*)d_in[9];
    const float* wky = (const float*)d_in[10];
    const float* bky = (const float*)d_in[11];
    const float* wvy = (const float*)d_in[12];
    const float* bvy = (const float*)d_in[13];
    const float* gx  = (const float*)d_in[14];
    const float* gy  = (const float*)d_in[15];
    ushort_t* ws = (ushort_t*)d_ws;
    float* out = (float*)d_out;

    wcvt_kernel<<<dim3(160), 256, 0, stream>>>(wqx, bqx, wkx, bkx, wvx, bvx,
                                               wqy, bqy, wky, bky, wvy, bvy, ws);
    proj_kernel<<<dim3(576), 256, 0, stream>>>(x, y, ws);
    flash_kernel<<<dim3(576), 256, 0, stream>>>(x, y, gx, gy, ws, out);
}